// Round 6
// baseline (102.198 us; speedup 1.0000x reference)
//
#include <hip/hip_runtime.h>
#include <hip/hip_bf16.h>
#include <math.h>

// ---------------------------------------------------------------------------
// PointerNet attention scorer, MI355X / gfx950.
//   1) proj_gemm: C = scale*(A@W^T + bias) on bf16 MFMA with in-staging
//      fp32->bf16 hi/lo split (3 passes: hiA*hiW + hiA*loW + loA*hiW,
//      rel err ~2^-16). Tile 64m x 64n, 384 blocks, 256 thr, single-buffered
//      LDS (R2/R5-proven mechanics). XCD-swizzled block ids: all 4 n-blocks
//      of one m-slice land on the same XCD -> A fetched once per XCD L2.
//      src -> spq h-quad-interleaved, query -> qp row-major.
//   2) attn_score: logit ~ -2*sum_h w2[h]/(exp2(sp'+qp')+1) (shift-invariant
//      terms b2 + sum(w2) dropped), masked softmax over S=128. XCD-swizzled
//      so the 16 t-chunks of one batch b share an XCD (spq L2 reuse).
// ---------------------------------------------------------------------------

#define TANH_PRESCALE 2.8853900817779268f   // 2*log2(e)
#define LOG2E        1.4426950408889634f

typedef __attribute__((ext_vector_type(8))) short short8;   // 8 bf16 = 4 VGPR
typedef __attribute__((ext_vector_type(4))) float f32x4;    // MFMA C/D frag

__device__ __forceinline__ float fast_exp2(float x) {
#if __has_builtin(__builtin_amdgcn_exp2f)
    return __builtin_amdgcn_exp2f(x);
#else
    return exp2f(x);
#endif
}
__device__ __forceinline__ float fast_rcp(float x) {
#if __has_builtin(__builtin_amdgcn_rcpf)
    return __builtin_amdgcn_rcpf(x);
#else
    return 1.0f / x;
#endif
}
__device__ __forceinline__ float hi_part(float x) {   // truncate to bf16 grid
    return __uint_as_float(__float_as_uint(x) & 0xffff0000u);
}
// pack bf16(a)=low16, bf16(b)=high16 (truncating) in one v_perm
__device__ __forceinline__ unsigned pack2(float a, float b) {
    return __builtin_amdgcn_perm(__float_as_uint(b), __float_as_uint(a), 0x07060302u);
}

// ---------------------------------------------------------------------------
// proj_gemm. 1-D grid of 384, XCD-swizzled decode:
//   g = lin&7 (XCD), r = lin>>3, nb = r&3, bx = (r>>2)*8 + g  (0..95)
// bx<64 -> src rows [bx*64,+64); else query rows. nb -> n in [nb*64,+64).
// 4 waves; wave wv -> (wm=wv&1, wn=wv>>1), wave tile 32m x 32n = 2x2
// 16x16x32 frags. K-loop: 8 tiles of BK=64 fp32, converted to hi/lo bf16
// in LDS during staging. LDS pitch 72 ushorts (144 B).
// ---------------------------------------------------------------------------
#define AHI 0
#define ALO 4608            // 64*72
#define WHI 9216
#define WLO 13824
#define LDS_USH 18432       // 36864 B

__global__ __launch_bounds__(256) void proj_gemm(
    const float* __restrict__ src, const float* __restrict__ query,
    const float* __restrict__ Wsrc, const float* __restrict__ Wq,
    const float* __restrict__ b_src, const float* __restrict__ b_q,
    float* __restrict__ spq, float* __restrict__ qp)
{
    // XCD-aware swizzle: keep all nb-blocks of one bx on one XCD.
    const int lin = blockIdx.x;           // 0..383
    const int g   = lin & 7;
    const int r   = lin >> 3;
    const int nb  = r & 3;                // 0..3
    const int bx  = (r >> 2) * 8 + g;     // 0..95

    const bool isSrc = bx < 64;
    const int mrow0 = (isSrc ? bx : bx - 64) * 64;
    const float* __restrict__ A    = isSrc ? src  : query;
    const float* __restrict__ W    = isSrc ? Wsrc : Wq;
    const float* __restrict__ bias = isSrc ? b_src : b_q;

    __shared__ unsigned short LS[LDS_USH];

    const int tid  = threadIdx.x;
    const int lane = tid & 63;
    const int wv   = tid >> 6;
    const int wm   = wv & 1, wn = wv >> 1;
    const int l15  = lane & 15;
    const int q4   = lane >> 4;       // 0..3

    const int srow = tid >> 3;        // staging rows p=0 (0..31); p=1 adds 32
    const int sc8  = tid & 7;

    f32x4 acc[2][2];
    #pragma unroll
    for (int i = 0; i < 2; ++i)
        #pragma unroll
        for (int j = 0; j < 2; ++j) acc[i][j] = (f32x4){0.f, 0.f, 0.f, 0.f};

    const float* Ab = A + (size_t)mrow0 * 512 + sc8 * 8;
    const float* Wb = W + (size_t)(nb * 64) * 512 + sc8 * 8;

    for (int kt = 0; kt < 512; kt += 64) {
        __syncthreads();   // previous tile's frag reads done
        #pragma unroll
        for (int p = 0; p < 2; ++p) {          // A: 64 rows x 64 k
            const int row = srow + 32 * p;
            const float* gp = Ab + (size_t)row * 512 + kt;
            float4 v0 = *(const float4*)gp, v1 = *(const float4*)(gp + 4);
            uint4 h; uint4 l;
            h.x = pack2(v0.x, v0.y);  h.y = pack2(v0.z, v0.w);
            h.z = pack2(v1.x, v1.y);  h.w = pack2(v1.z, v1.w);
            l.x = pack2(v0.x - hi_part(v0.x), v0.y - hi_part(v0.y));
            l.y = pack2(v0.z - hi_part(v0.z), v0.w - hi_part(v0.w));
            l.z = pack2(v1.x - hi_part(v1.x), v1.y - hi_part(v1.y));
            l.w = pack2(v1.z - hi_part(v1.z), v1.w - hi_part(v1.w));
            *(uint4*)&LS[AHI + row * 72 + sc8 * 8] = h;
            *(uint4*)&LS[ALO + row * 72 + sc8 * 8] = l;
        }
        #pragma unroll
        for (int p = 0; p < 2; ++p) {          // W: 64 rows x 64 k
            const int row = srow + 32 * p;
            const float* gp = Wb + (size_t)row * 512 + kt;
            float4 v0 = *(const float4*)gp, v1 = *(const float4*)(gp + 4);
            uint4 h; uint4 l;
            h.x = pack2(v0.x, v0.y);  h.y = pack2(v0.z, v0.w);
            h.z = pack2(v1.x, v1.y);  h.w = pack2(v1.z, v1.w);
            l.x = pack2(v0.x - hi_part(v0.x), v0.y - hi_part(v0.y));
            l.y = pack2(v0.z - hi_part(v0.z), v0.w - hi_part(v0.w));
            l.z = pack2(v1.x - hi_part(v1.x), v1.y - hi_part(v1.y));
            l.w = pack2(v1.z - hi_part(v1.z), v1.w - hi_part(v1.w));
            *(uint4*)&LS[WHI + row * 72 + sc8 * 8] = h;
            *(uint4*)&LS[WLO + row * 72 + sc8 * 8] = l;
        }
        __syncthreads();

        #pragma unroll
        for (int pass = 0; pass < 3; ++pass) {
            const unsigned short* Ap = LS + (pass == 2 ? ALO : AHI);
            const unsigned short* Wp = LS + (pass == 1 ? WLO : WHI);
            #pragma unroll
            for (int kk = 0; kk < 2; ++kk) {
                const int off = (kk * 4 + q4) * 8;    // ushort k-octet offset
                short8 a0 = *(const short8*)&Ap[(wm * 32 + l15)      * 72 + off];
                short8 a1 = *(const short8*)&Ap[(wm * 32 + 16 + l15) * 72 + off];
                short8 w0 = *(const short8*)&Wp[(wn * 32 + l15)      * 72 + off];
                short8 w1 = *(const short8*)&Wp[(wn * 32 + 16 + l15) * 72 + off];
                acc[0][0] = __builtin_amdgcn_mfma_f32_16x16x32_bf16(a0, w0, acc[0][0], 0, 0, 0);
                acc[0][1] = __builtin_amdgcn_mfma_f32_16x16x32_bf16(a0, w1, acc[0][1], 0, 0, 0);
                acc[1][0] = __builtin_amdgcn_mfma_f32_16x16x32_bf16(a1, w0, acc[1][0], 0, 0, 0);
                acc[1][1] = __builtin_amdgcn_mfma_f32_16x16x32_bf16(a1, w1, acc[1][1], 0, 0, 0);
            }
        }
    }

    float bl[2];
    #pragma unroll
    for (int ni = 0; ni < 2; ++ni)
        bl[ni] = bias[nb * 64 + wn * 32 + ni * 16 + l15];

    __syncthreads();                 // frag reads done before E overwrites LDS
    float* E = (float*)LS;           // 64 x 68 fp32 = 17408 B
    #pragma unroll
    for (int mi = 0; mi < 2; ++mi)
        #pragma unroll
        for (int ni = 0; ni < 2; ++ni) {
            const int m = wm * 32 + mi * 16 + q4 * 4;   // C/D: row=(lane>>4)*4+r
            const int n = wn * 32 + ni * 16 + l15;      //      col=lane&15
            #pragma unroll
            for (int rr = 0; rr < 4; ++rr)
                E[(m + rr) * 68 + n] = (acc[mi][ni][rr] + bl[ni]) * TANH_PRESCALE;
        }
    __syncthreads();

    if (isSrc) {
        // h-quad-interleaved: spq[(nb*16+nq)*16384 + (mrow0+m)*4 + (n&3)]
        const int nq = tid >> 4;                     // 0..15
        #pragma unroll
        for (int j = 0; j < 4; ++j) {
            const int m = (tid & 15) + 16 * j;       // 0..63
            float4 v = *(const float4*)&E[m * 68 + nq * 4];
            *(float4*)(spq + (size_t)(nb * 16 + nq) * 16384
                           + (size_t)(mrow0 + m) * 4) = v;
        }
    } else {
        // row-major qp[(mrow0+m)*256 + nb*64 + n]
        #pragma unroll
        for (int p = 0; p < 4; ++p) {
            const int idx = p * 256 + tid;
            const int m = idx >> 4, c4 = idx & 15;
            float4 v = *(const float4*)&E[m * 68 + c4 * 4];
            *(float4*)(qp + (size_t)(mrow0 + m) * 256 + nb * 64 + c4 * 4) = v;
        }
    }
}

// ---------------------------------------------------------------------------
// Fused score + masked softmax. 1-D grid of 512, XCD-swizzled decode:
//   g = lin&7, r = lin>>3, tz = r&15, b = (r>>4)*8 + g  (0..31)
// -> all 16 t-chunks of one b share an XCD (spq slice reused from L2).
// 512 thr (8 waves); thread (s, h-group g4 of 64) carries 4 t-accumulators;
// partials combined in LDS; per-wave softmax over S=128 in waves 0..3.
// ---------------------------------------------------------------------------
__global__ __launch_bounds__(512) void attn_score(
    const float* __restrict__ spq, const float* __restrict__ qp,
    const float* __restrict__ w2, const int* __restrict__ mask,
    float* __restrict__ out)
{
    const int lin = blockIdx.x;           // 0..511
    const int gx  = lin & 7;
    const int rr  = lin >> 3;
    const int tz  = rr & 15;              // 0..15
    const int b   = (rr >> 4) * 8 + gx;   // 0..31

    const int tid = threadIdx.x;

    __shared__ float qp_s[4][256];
    __shared__ float w2_s[256];
    __shared__ float h2p[4][4][128];   // [h-group][t-local][s]

    int mk0 = 0, mk1 = 0;
    if (tid < 256) {
        const int tl = tid >> 6, lane = tid & 63;
        const int t = tz * 4 + tl;
        *(float4*)&qp_s[tl][lane * 4] =
            *(const float4*)(qp + (size_t)(t * 32 + b) * 256 + lane * 4);
        mk0 = mask[b * 128 + lane];
        mk1 = mask[b * 128 + lane + 64];
    } else if (tid < 320) {
        const int i = tid - 256;
        *(float4*)&w2_s[i * 4] = *(const float4*)(w2 + i * 4);
    }
    __syncthreads();

    const int s = tid & 127;
    const int g4 = tid >> 7;           // 0..3 -> h in [g4*64, g4*64+64)
    const int hb = g4 * 64;
    const float* sq = spq + (size_t)(g4 * 16) * 16384 + (size_t)(b * 128 + s) * 4;

    float acc0 = 0.f, acc1 = 0.f, acc2 = 0.f, acc3 = 0.f;
    float4 s4 = *(const float4*)sq;                 // prefetch hq=0
    #pragma unroll 4
    for (int hq = 0; hq < 16; ++hq) {
        float4 nxt;
        if (hq < 15) nxt = *(const float4*)(sq + (size_t)(hq + 1) * 16384);
        float4 w4 = *(const float4*)&w2_s[hb + hq * 4];
        float4 q0 = *(const float4*)&qp_s[0][hb + hq * 4];
        float4 q1 = *(const float4*)&qp_s[1][hb + hq * 4];
        float4 q2 = *(const float4*)&qp_s[2][hb + hq * 4];
        float4 q3 = *(const float4*)&qp_s[3][hb + hq * 4];
        #define PN_TERM(sj, wj, q0j, q1j, q2j, q3j)                              \
            { float r_;                                                          \
              r_ = fast_rcp(fast_exp2(sj + q0j) + 1.0f); acc0 = fmaf(wj, r_, acc0);\
              r_ = fast_rcp(fast_exp2(sj + q1j) + 1.0f); acc1 = fmaf(wj, r_, acc1);\
              r_ = fast_rcp(fast_exp2(sj + q2j) + 1.0f); acc2 = fmaf(wj, r_, acc2);\
              r_ = fast_rcp(fast_exp2(sj + q3j) + 1.0f); acc3 = fmaf(wj, r_, acc3); }
        PN_TERM(s4.x, w4.x, q0.x, q1.x, q2.x, q3.x)
        PN_TERM(s4.y, w4.y, q0.y, q1.y, q2.y, q3.y)
        PN_TERM(s4.z, w4.z, q0.z, q1.z, q2.z, q3.z)
        PN_TERM(s4.w, w4.w, q0.w, q1.w, q2.w, q3.w)
        #undef PN_TERM
        s4 = nxt;
    }
    h2p[g4][0][s] = acc0;
    h2p[g4][1][s] = acc1;
    h2p[g4][2][s] = acc2;
    h2p[g4][3][s] = acc3;
    __syncthreads();

    if (tid < 256) {
        const int wv = tid >> 6, lane = tid & 63;
        float v0 = -2.0f * (h2p[0][wv][lane] + h2p[1][wv][lane]
                          + h2p[2][wv][lane] + h2p[3][wv][lane]);
        float v1 = -2.0f * (h2p[0][wv][lane + 64] + h2p[1][wv][lane + 64]
                          + h2p[2][wv][lane + 64] + h2p[3][wv][lane + 64]);
        if (mk0) v0 = -__builtin_inff();
        if (mk1) v1 = -__builtin_inff();

        float mx = fmaxf(v0, v1);
        #pragma unroll
        for (int off = 32; off >= 1; off >>= 1) mx = fmaxf(mx, __shfl_xor(mx, off));
        float e0 = fast_exp2((v0 - mx) * LOG2E);   // -inf -> 0
        float e1 = fast_exp2((v1 - mx) * LOG2E);
        float sum = e0 + e1;
        #pragma unroll
        for (int off = 32; off >= 1; off >>= 1) sum += __shfl_xor(sum, off);
        const float r_ = fast_rcp(sum);

        const size_t ob = (size_t)((tz * 4 + wv) * 32 + b) * 128;
        out[ob + lane]      = e0 * r_;
        out[ob + lane + 64] = e1 * r_;
    }
}

extern "C" void kernel_launch(void* const* d_in, const int* in_sizes, int n_in,
                              void* d_out, int out_size, void* d_ws, size_t ws_size,
                              hipStream_t stream) {
    const float* src   = (const float*)d_in[0];   // (B,S,E)
    const int*   mask  = (const int*)  d_in[1];   // (B,S)
    const float* query = (const float*)d_in[2];   // (T,B,Q)
    const float* W_src = (const float*)d_in[3];   // (H,E)
    const float* b_src = (const float*)d_in[4];
    const float* W_q   = (const float*)d_in[5];   // (H,Q)
    const float* b_q   = (const float*)d_in[6];
    const float* w2    = (const float*)d_in[7];
    // d_in[8] = b2 : unused (softmax shift-invariant)
    float* out = (float*)d_out;

    // ws: spq 4 MB @0 | qp 2 MB @4MB (minimal footprint; ws is cold-poisoned)
    float* spq = (float*)d_ws;
    float* qp  = (float*)((char*)d_ws + (4u << 20));

    proj_gemm<<<384, 256, 0, stream>>>(src, query, W_src, W_q,
                                       b_src, b_q, spq, qp);
    attn_score<<<512, 512, 0, stream>>>(spq, qp, w2, mask, out);
}

// Round 7
// 101.902 us; speedup vs baseline: 1.0029x; 1.0029x over previous
//
#include <hip/hip_runtime.h>
#include <hip/hip_bf16.h>
#include <math.h>

// ---------------------------------------------------------------------------
// PointerNet attention scorer, MI355X / gfx950.
//   1) proj_gemm: C = scale*(A@W^T + bias) on bf16 MFMA with in-staging
//      fp32->bf16 hi/lo split (3 passes: hiA*hiW + hiA*loW + loA*hiW,
//      rel err ~2^-16). Tile 64m x 64n, grid (96,4)=384 blocks, 256 thr,
//      single-buffered LDS (R2/R5-proven mechanics — byte-identical to the
//      101.2 us R5 version). src -> spq h-quad-interleaved, query -> qp.
//   2) attn_score: logit ~ -2*sum_h w2[h]/(exp2(sp'+qp')+1) (shift-invariant
//      terms b2 + sum(w2) dropped), masked softmax over S=128.
//      R7: double-buffered cooperative LDS pipeline for spq (8 phases of
//      8 hq x 128 s), register-held global loads overlapping compute —
//      removes the per-thread serial strided-load chain of R6.
// ---------------------------------------------------------------------------

#define TANH_PRESCALE 2.8853900817779268f   // 2*log2(e)
#define LOG2E        1.4426950408889634f

typedef __attribute__((ext_vector_type(8))) short short8;   // 8 bf16 = 4 VGPR
typedef __attribute__((ext_vector_type(4))) float f32x4;    // MFMA C/D frag

__device__ __forceinline__ float fast_exp2(float x) {
#if __has_builtin(__builtin_amdgcn_exp2f)
    return __builtin_amdgcn_exp2f(x);
#else
    return exp2f(x);
#endif
}
__device__ __forceinline__ float fast_rcp(float x) {
#if __has_builtin(__builtin_amdgcn_rcpf)
    return __builtin_amdgcn_rcpf(x);
#else
    return 1.0f / x;
#endif
}
__device__ __forceinline__ float hi_part(float x) {   // truncate to bf16 grid
    return __uint_as_float(__float_as_uint(x) & 0xffff0000u);
}
// pack bf16(a)=low16, bf16(b)=high16 (truncating) in one v_perm
__device__ __forceinline__ unsigned pack2(float a, float b) {
    return __builtin_amdgcn_perm(__float_as_uint(b), __float_as_uint(a), 0x07060302u);
}

// ---------------------------------------------------------------------------
// proj_gemm — unchanged from R5 (proven fastest variant).
// ---------------------------------------------------------------------------
#define AHI 0
#define ALO 4608            // 64*72
#define WHI 9216
#define WLO 13824
#define LDS_USH 18432       // 36864 B

__global__ __launch_bounds__(256) void proj_gemm(
    const float* __restrict__ src, const float* __restrict__ query,
    const float* __restrict__ Wsrc, const float* __restrict__ Wq,
    const float* __restrict__ b_src, const float* __restrict__ b_q,
    float* __restrict__ spq, float* __restrict__ qp)
{
    const int bx = blockIdx.x;        // 0..95
    const int nb = blockIdx.y;        // 0..3
    const bool isSrc = bx < 64;
    const int mrow0 = (isSrc ? bx : bx - 64) * 64;
    const float* __restrict__ A    = isSrc ? src  : query;
    const float* __restrict__ W    = isSrc ? Wsrc : Wq;
    const float* __restrict__ bias = isSrc ? b_src : b_q;

    __shared__ unsigned short LS[LDS_USH];

    const int tid  = threadIdx.x;
    const int lane = tid & 63;
    const int wv   = tid >> 6;
    const int wm   = wv & 1, wn = wv >> 1;
    const int l15  = lane & 15;
    const int q4   = lane >> 4;       // 0..3

    const int srow = tid >> 3;        // staging rows p=0 (0..31); p=1 adds 32
    const int sc8  = tid & 7;

    f32x4 acc[2][2];
    #pragma unroll
    for (int i = 0; i < 2; ++i)
        #pragma unroll
        for (int j = 0; j < 2; ++j) acc[i][j] = (f32x4){0.f, 0.f, 0.f, 0.f};

    const float* Ab = A + (size_t)mrow0 * 512 + sc8 * 8;
    const float* Wb = W + (size_t)(nb * 64) * 512 + sc8 * 8;

    for (int kt = 0; kt < 512; kt += 64) {
        __syncthreads();   // previous tile's frag reads done
        #pragma unroll
        for (int p = 0; p < 2; ++p) {          // A: 64 rows x 64 k
            const int row = srow + 32 * p;
            const float* gp = Ab + (size_t)row * 512 + kt;
            float4 v0 = *(const float4*)gp, v1 = *(const float4*)(gp + 4);
            uint4 h; uint4 l;
            h.x = pack2(v0.x, v0.y);  h.y = pack2(v0.z, v0.w);
            h.z = pack2(v1.x, v1.y);  h.w = pack2(v1.z, v1.w);
            l.x = pack2(v0.x - hi_part(v0.x), v0.y - hi_part(v0.y));
            l.y = pack2(v0.z - hi_part(v0.z), v0.w - hi_part(v0.w));
            l.z = pack2(v1.x - hi_part(v1.x), v1.y - hi_part(v1.y));
            l.w = pack2(v1.z - hi_part(v1.z), v1.w - hi_part(v1.w));
            *(uint4*)&LS[AHI + row * 72 + sc8 * 8] = h;
            *(uint4*)&LS[ALO + row * 72 + sc8 * 8] = l;
        }
        #pragma unroll
        for (int p = 0; p < 2; ++p) {          // W: 64 rows x 64 k
            const int row = srow + 32 * p;
            const float* gp = Wb + (size_t)row * 512 + kt;
            float4 v0 = *(const float4*)gp, v1 = *(const float4*)(gp + 4);
            uint4 h; uint4 l;
            h.x = pack2(v0.x, v0.y);  h.y = pack2(v0.z, v0.w);
            h.z = pack2(v1.x, v1.y);  h.w = pack2(v1.z, v1.w);
            l.x = pack2(v0.x - hi_part(v0.x), v0.y - hi_part(v0.y));
            l.y = pack2(v0.z - hi_part(v0.z), v0.w - hi_part(v0.w));
            l.z = pack2(v1.x - hi_part(v1.x), v1.y - hi_part(v1.y));
            l.w = pack2(v1.z - hi_part(v1.z), v1.w - hi_part(v1.w));
            *(uint4*)&LS[WHI + row * 72 + sc8 * 8] = h;
            *(uint4*)&LS[WLO + row * 72 + sc8 * 8] = l;
        }
        __syncthreads();

        #pragma unroll
        for (int pass = 0; pass < 3; ++pass) {
            const unsigned short* Ap = LS + (pass == 2 ? ALO : AHI);
            const unsigned short* Wp = LS + (pass == 1 ? WLO : WHI);
            #pragma unroll
            for (int kk = 0; kk < 2; ++kk) {
                const int off = (kk * 4 + q4) * 8;    // ushort k-octet offset
                short8 a0 = *(const short8*)&Ap[(wm * 32 + l15)      * 72 + off];
                short8 a1 = *(const short8*)&Ap[(wm * 32 + 16 + l15) * 72 + off];
                short8 w0 = *(const short8*)&Wp[(wn * 32 + l15)      * 72 + off];
                short8 w1 = *(const short8*)&Wp[(wn * 32 + 16 + l15) * 72 + off];
                acc[0][0] = __builtin_amdgcn_mfma_f32_16x16x32_bf16(a0, w0, acc[0][0], 0, 0, 0);
                acc[0][1] = __builtin_amdgcn_mfma_f32_16x16x32_bf16(a0, w1, acc[0][1], 0, 0, 0);
                acc[1][0] = __builtin_amdgcn_mfma_f32_16x16x32_bf16(a1, w0, acc[1][0], 0, 0, 0);
                acc[1][1] = __builtin_amdgcn_mfma_f32_16x16x32_bf16(a1, w1, acc[1][1], 0, 0, 0);
            }
        }
    }

    float bl[2];
    #pragma unroll
    for (int ni = 0; ni < 2; ++ni)
        bl[ni] = bias[nb * 64 + wn * 32 + ni * 16 + l15];

    __syncthreads();                 // frag reads done before E overwrites LDS
    float* E = (float*)LS;           // 64 x 68 fp32 = 17408 B
    #pragma unroll
    for (int mi = 0; mi < 2; ++mi)
        #pragma unroll
        for (int ni = 0; ni < 2; ++ni) {
            const int m = wm * 32 + mi * 16 + q4 * 4;   // C/D: row=(lane>>4)*4+r
            const int n = wn * 32 + ni * 16 + l15;      //      col=lane&15
            #pragma unroll
            for (int rr = 0; rr < 4; ++rr)
                E[(m + rr) * 68 + n] = (acc[mi][ni][rr] + bl[ni]) * TANH_PRESCALE;
        }
    __syncthreads();

    if (isSrc) {
        // h-quad-interleaved: spq[(nb*16+nq)*16384 + (mrow0+m)*4 + (n&3)]
        const int nq = tid >> 4;                     // 0..15
        #pragma unroll
        for (int j = 0; j < 4; ++j) {
            const int m = (tid & 15) + 16 * j;       // 0..63
            float4 v = *(const float4*)&E[m * 68 + nq * 4];
            *(float4*)(spq + (size_t)(nb * 16 + nq) * 16384
                           + (size_t)(mrow0 + m) * 4) = v;
        }
    } else {
        // row-major qp[(mrow0+m)*256 + nb*64 + n]
        #pragma unroll
        for (int p = 0; p < 4; ++p) {
            const int idx = p * 256 + tid;
            const int m = idx >> 4, c4 = idx & 15;
            float4 v = *(const float4*)&E[m * 68 + c4 * 4];
            *(float4*)(qp + (size_t)(mrow0 + m) * 256 + nb * 64 + c4 * 4) = v;
        }
    }
}

// ---------------------------------------------------------------------------
// attn_score v3: double-buffered LDS pipeline.
// Block = (b, 4-t chunk), grid 512 (2 blocks/CU), 512 thr (8 waves).
// Thread = (s 0..127, g4 0..3 covering h in [g4*64, +64)), 4 t-accumulators.
// 8 phases; phase p stages, for every g4, its global-hq pair
// {g4*16 + p*2, +1} -> LDS slot {g4*2, g4*2+1}. Loads for p+1 are held in
// registers across compute(p). All inner math is LDS/broadcast + trans pipe.
// Accumulation order (hq ascending per g4) identical to R6 -> bitwise-same.
// ---------------------------------------------------------------------------
__global__ __launch_bounds__(512) void attn_score(
    const float* __restrict__ spq, const float* __restrict__ qp,
    const float* __restrict__ w2, const int* __restrict__ mask,
    float* __restrict__ out)
{
    const int lin = blockIdx.x;   // 0..511
    const int b   = lin & 31;
    const int tz  = lin >> 5;     // 0..15

    const int tid = threadIdx.x;

    __shared__ float4 spq_s[2][8][128];   // 32 KB (dbuf x 8 hq-slots x 128 s)
    __shared__ float  qp_s[4][256];       // 4 KB
    __shared__ float  w2_s[256];          // 1 KB
    __shared__ float  h2p[4][4][128];     // 8 KB [h-group][t-local][s]

    int mk0 = 0, mk1 = 0;
    if (tid < 256) {
        const int tl = tid >> 6, lane = tid & 63;
        const int t = tz * 4 + tl;
        *(float4*)&qp_s[tl][lane * 4] =
            *(const float4*)(qp + (size_t)(t * 32 + b) * 256 + lane * 4);
        mk0 = mask[b * 128 + lane];
        mk1 = mask[b * 128 + lane + 64];
    } else if (tid < 320) {
        const int i = tid - 256;
        *(float4*)&w2_s[i * 4] = *(const float4*)(w2 + i * 4);
    }

    // staging lane constants: idx = j*512 + tid, j=0,1 -> (slot, s)
    const int slot0 = tid >> 7;             // 0..3  (j=0)
    const int slot1 = 4 + (tid >> 7);       // 4..7  (j=1)
    const int s_i   = tid & 127;
    // global hq for slot q at phase p: (q>>1)*16 + p*2 + (q&1)
    const float* sp_b = spq + (size_t)(b * 128 + s_i) * 4;
    #define GHQ(q, p) (((q) >> 1) * 16 + (p) * 2 + ((q) & 1))
    #define GLOAD(q, p) (*(const float4*)(sp_b + (size_t)GHQ(q, p) * 16384))

    // prologue: stage phase 0 into buf 0
    {
        float4 r0 = GLOAD(slot0, 0);
        float4 r1 = GLOAD(slot1, 0);
        spq_s[0][slot0][s_i] = r0;
        spq_s[0][slot1][s_i] = r1;
    }
    __syncthreads();

    const int s  = tid & 127;
    const int g4 = tid >> 7;            // 0..3
    const int hb = g4 * 64;

    float acc0 = 0.f, acc1 = 0.f, acc2 = 0.f, acc3 = 0.f;

    #pragma unroll
    for (int p = 0; p < 8; ++p) {
        float4 r0, r1;
        if (p < 7) {                    // issue next phase's loads now
            r0 = GLOAD(slot0, p + 1);
            r1 = GLOAD(slot1, p + 1);
        }
        const int buf = p & 1;
        #pragma unroll
        for (int k = 0; k < 2; ++k) {   // two hq per phase per g4
            const int hq = p * 2 + k;               // local hq 0..15
            float4 s4 = spq_s[buf][g4 * 2 + k][s];
            float4 w4 = *(const float4*)&w2_s[hb + hq * 4];
            float4 q0 = *(const float4*)&qp_s[0][hb + hq * 4];
            float4 q1 = *(const float4*)&qp_s[1][hb + hq * 4];
            float4 q2 = *(const float4*)&qp_s[2][hb + hq * 4];
            float4 q3 = *(const float4*)&qp_s[3][hb + hq * 4];
            #define PN_TERM(sj, wj, q0j, q1j, q2j, q3j)                              \
                { float r_;                                                          \
                  r_ = fast_rcp(fast_exp2(sj + q0j) + 1.0f); acc0 = fmaf(wj, r_, acc0);\
                  r_ = fast_rcp(fast_exp2(sj + q1j) + 1.0f); acc1 = fmaf(wj, r_, acc1);\
                  r_ = fast_rcp(fast_exp2(sj + q2j) + 1.0f); acc2 = fmaf(wj, r_, acc2);\
                  r_ = fast_rcp(fast_exp2(sj + q3j) + 1.0f); acc3 = fmaf(wj, r_, acc3); }
            PN_TERM(s4.x, w4.x, q0.x, q1.x, q2.x, q3.x)
            PN_TERM(s4.y, w4.y, q0.y, q1.y, q2.y, q3.y)
            PN_TERM(s4.z, w4.z, q0.z, q1.z, q2.z, q3.z)
            PN_TERM(s4.w, w4.w, q0.w, q1.w, q2.w, q3.w)
            #undef PN_TERM
        }
        if (p < 7) {
            __syncthreads();            // compute(p) done everywhere -> buf^1 free
            spq_s[buf ^ 1][slot0][s_i] = r0;
            spq_s[buf ^ 1][slot1][s_i] = r1;
            __syncthreads();            // staged visible
        }
    }

    h2p[g4][0][s] = acc0;
    h2p[g4][1][s] = acc1;
    h2p[g4][2][s] = acc2;
    h2p[g4][3][s] = acc3;
    __syncthreads();

    if (tid < 256) {
        const int wv = tid >> 6, lane = tid & 63;
        float v0 = -2.0f * (h2p[0][wv][lane] + h2p[1][wv][lane]
                          + h2p[2][wv][lane] + h2p[3][wv][lane]);
        float v1 = -2.0f * (h2p[0][wv][lane + 64] + h2p[1][wv][lane + 64]
                          + h2p[2][wv][lane + 64] + h2p[3][wv][lane + 64]);
        if (mk0) v0 = -__builtin_inff();
        if (mk1) v1 = -__builtin_inff();

        float mx = fmaxf(v0, v1);
        #pragma unroll
        for (int off = 32; off >= 1; off >>= 1) mx = fmaxf(mx, __shfl_xor(mx, off));
        float e0 = fast_exp2((v0 - mx) * LOG2E);   // -inf -> 0
        float e1 = fast_exp2((v1 - mx) * LOG2E);
        float sum = e0 + e1;
        #pragma unroll
        for (int off = 32; off >= 1; off >>= 1) sum += __shfl_xor(sum, off);
        const float r_ = fast_rcp(sum);

        const size_t ob = (size_t)((tz * 4 + wv) * 32 + b) * 128;
        out[ob + lane]      = e0 * r_;
        out[ob + lane + 64] = e1 * r_;
    }
}

extern "C" void kernel_launch(void* const* d_in, const int* in_sizes, int n_in,
                              void* d_out, int out_size, void* d_ws, size_t ws_size,
                              hipStream_t stream) {
    const float* src   = (const float*)d_in[0];   // (B,S,E)
    const int*   mask  = (const int*)  d_in[1];   // (B,S)
    const float* query = (const float*)d_in[2];   // (T,B,Q)
    const float* W_src = (const float*)d_in[3];   // (H,E)
    const float* b_src = (const float*)d_in[4];
    const float* W_q   = (const float*)d_in[5];   // (H,Q)
    const float* b_q   = (const float*)d_in[6];
    const float* w2    = (const float*)d_in[7];
    // d_in[8] = b2 : unused (softmax shift-invariant)
    float* out = (float*)d_out;

    // ws: spq 4 MB @0 | qp 2 MB @4MB (minimal footprint; ws is cold-poisoned)
    float* spq = (float*)d_ws;
    float* qp  = (float*)((char*)d_ws + (4u << 20));

    proj_gemm<<<dim3(96, 4), 256, 0, stream>>>(src, query, W_src, W_q,
                                               b_src, b_q, spq, qp);
    attn_score<<<512, 512, 0, stream>>>(spq, qp, w2, mask, out);
}